// Round 2
// baseline (121.181 us; speedup 1.0000x reference)
//
#include <hip/hip_runtime.h>

#define D_IN   1024
#define D_PROJ 256
#define N_C    64
#define N_ROWS 16384
#define BM     32
#define BK     64
#define A_STRIDE 72     // BK + 8 pad (bf16 elems) -> 144 B rows, uniform banks
#define Z_STRIDE 264    // D_PROJ + 8 pad -> 528 B rows
#define BSZ (D_PROJ * BK)     // shorts per B buffer (16384 = 32 KB)
#define ASZ (BM * A_STRIDE)   // shorts per A buffer (2304)

typedef float v4f __attribute__((ext_vector_type(4)));
typedef short v8s __attribute__((ext_vector_type(8)));

__device__ inline unsigned short f2bf(float f) {
  unsigned int u = __float_as_uint(f);
  u = u + 0x7fffu + ((u >> 16) & 1u);   // round-to-nearest-even
  return (unsigned short)(u >> 16);
}

__device__ inline void async16(const void* g, void* s) {
  __builtin_amdgcn_global_load_lds(
      (const __attribute__((address_space(1))) unsigned int*)g,
      (__attribute__((address_space(3))) unsigned int*)s, 16, 0, 0);
}

// counted-vmcnt barrier: drains lgkm (A ds_write) + all but N newest VMEM ops.
// N=4 is used when 4 X-prefetch loads (issued AFTER the B stage) must stay in flight.
#define KBAR(N) do {                                                     \
  asm volatile("s_waitcnt vmcnt(" #N ") lgkmcnt(0)" ::: "memory");       \
  __builtin_amdgcn_s_barrier();                                          \
  __builtin_amdgcn_sched_barrier(0);                                     \
} while (0)

// ---------------------------------------------------------------------------
// Prep: projT bf16 [256][1024] (transposed), protoB bf16 [64][256], pnorm2[64],
//       mu_p[256] = mean @ proj (fp32)
// grid 96 x 256: blocks 0..63 transpose, 64..79 protos, 80..95 mu_p
// ---------------------------------------------------------------------------
__global__ __launch_bounds__(256) void prep_kernel(
    const float* __restrict__ proj,      // [1024][256]
    const float* __restrict__ protos,    // [64][256]
    const float* __restrict__ mean,      // [1024]
    unsigned short* __restrict__ projT,  // [256][1024]
    unsigned short* __restrict__ protoB, // [64][256]
    float* __restrict__ pnorm2,          // [64]
    float* __restrict__ mu_p)            // [256]
{
  __shared__ float tile[64][65];
  __shared__ float part[16][17];
  const int b = blockIdx.x;
  const int t = threadIdx.x;
  if (b < 64) {
    const int k0 = (b & 15) * 64, n0 = (b >> 4) * 64;
    const int r = t >> 4, c4 = (t & 15) * 4;
    for (int rr = r; rr < 64; rr += 16) {
      const float4 v = *(const float4*)(proj + (k0 + rr) * D_PROJ + n0 + c4);
      tile[rr][c4 + 0] = v.x; tile[rr][c4 + 1] = v.y;
      tile[rr][c4 + 2] = v.z; tile[rr][c4 + 3] = v.w;
    }
    __syncthreads();
    const int n = t >> 2, kc = (t & 3) * 16;
    unsigned short o[16];
#pragma unroll
    for (int i = 0; i < 16; ++i) o[i] = f2bf(tile[kc + i][n]);
    unsigned short* dst = projT + (n0 + n) * D_IN + k0 + kc;
#pragma unroll
    for (int i = 0; i < 4; ++i) {
      ushort4 s4 = { o[4*i+0], o[4*i+1], o[4*i+2], o[4*i+3] };
      *(ushort4*)(dst + 4*i) = s4;
    }
  } else if (b < 80) {
    const int w = t >> 6, l = t & 63;
    const int c = (b - 64) * 4 + w;                    // proto 0..63
    const float4 v = *(const float4*)(protos + c * D_PROJ + l * 4);
    float ss = v.x*v.x + v.y*v.y + v.z*v.z + v.w*v.w;
#pragma unroll
    for (int m = 1; m < 64; m <<= 1) ss += __shfl_xor(ss, m);
    if (l == 0) pnorm2[c] = ss;
    ushort4 o = { f2bf(v.x), f2bf(v.y), f2bf(v.z), f2bf(v.w) };
    *(ushort4*)(protoB + c * D_PROJ + l * 4) = o;
  } else {
    // mu_p: 16 blocks x 16 cols each; 16-way k-split per col
    const int b2  = b - 80;
    const int col = b2 * 16 + (t & 15);
    const int ks  = t >> 4;
    float s = 0.0f;
    const int kb = ks * 64;
#pragma unroll 4
    for (int k = 0; k < 64; ++k)
      s = fmaf(mean[kb + k], proj[(kb + k) * D_PROJ + col], s);
    part[ks][t & 15] = s;
    __syncthreads();
    if (t < 16) {
      float acc = 0.0f;
#pragma unroll
      for (int i = 0; i < 16; ++i) acc += part[i][t];
      mu_p[b2 * 16 + t] = acc;
    }
  }
}

// ---------------------------------------------------------------------------
// Main fused kernel: 32 rows/block, 512 blocks, 512 threads (8 waves)
// wave w: rg = w>>2 (row half, 16 rows), cg = w&3 (64-col / proto group)
//
// R1 restructure: double-buffered B (2x32KB) + A (2x4.5KB), ONE barrier per
// k-tile (16+1 vs 32), stage tile kt+1 BEFORE computing tile kt so the L2
// B-stage latency hides under compute. X prefetch loads are issued AFTER the
// B stage at kt=2,6,10 and exempted from that barrier via vmcnt(4) (they are
// the 4 newest VMEM ops; the counted wait retires only the older B stages).
// lds_P dropped (protos read direct from L1/L2-hot protoB in GEMM2) to keep
// LDS at ~75.5 KB -> 2 blocks/CU.
// ---------------------------------------------------------------------------
__global__ __launch_bounds__(512, 4) void protonet_main(
    const float* __restrict__ X,               // [16384][1024]
    const unsigned short* __restrict__ projT,  // [256][1024] bf16
    const unsigned short* __restrict__ protoB, // [64][256]   bf16
    const float* __restrict__ pnorm2,          // [64]
    const float* __restrict__ mu_p,            // [256]
    float* __restrict__ out)                   // [16384][64]
{
  __shared__ unsigned short lds_A[2 * ASZ];   // 9.2 KB, padded, double-buffered
  __shared__ unsigned short lds_B[2 * BSZ];   // 64 KB, swizzled, double-buffered
  __shared__ float lds_part[4][BM];
  __shared__ float lds_inv[BM];
  __shared__ float lds_z2[BM];

  const int t  = threadIdx.x;
  const int w  = t >> 6;
  const int l  = t & 63;
  const int q  = l >> 4;
  const int lc = l & 15;
  const int rg = w >> 2;      // 0..1 row group (16 rows)
  const int cg = w & 3;       // 0..3 col group (64 cols) / proto group (16)
  const int row0 = blockIdx.x * BM;

  // per-lane invariant src index for B staging:
  // instr s: row n = 32w + 8s + (l>>3), phys chunk p = l&7, logical = p^(n&7)
  const int bsrc0 = ((w << 5) + (l >> 3)) * D_IN + (((l & 7) ^ ((l >> 3) & 7)) << 3);
  const int bdst0 = (w << 5) * BK;   // + (s<<3)*BK per instr

  // A: thread owns row ar, float4 slot aj
  const int ar = t >> 4;
  const int aj = t & 15;
  const float* xbase = X + (row0 + ar) * D_IN + (aj << 2);

  ushort4 abf[16];     // bf16 A slices, one per k-tile (32 VGPRs)
  float4  xf[4];       // in-flight X chunk (16 VGPRs)

  // ---- prologue: load+convert chunk0, stage tile0 into buf0 ----
#pragma unroll
  for (int i = 0; i < 4; ++i) xf[i] = *(const float4*)(xbase + i * BK);
#pragma unroll
  for (int i = 0; i < 4; ++i) {
    const float4 v = xf[i];
    ushort4 o = { f2bf(v.x), f2bf(v.y), f2bf(v.z), f2bf(v.w) };
    abf[i] = o;
  }
#pragma unroll
  for (int s = 0; s < 4; ++s)
    async16(projT + bsrc0 + s * (8 * D_IN), lds_B + bdst0 + (s << 3) * BK);
  *(ushort4*)(lds_A + ar * A_STRIDE + (aj << 2)) = abf[0];
  __syncthreads();

  v4f acc1[4];
#pragma unroll
  for (int j = 0; j < 4; ++j) acc1[j] = (v4f)(0.0f);

#pragma unroll
  for (int kt = 0; kt < 16; ++kt) {
    const int cur = kt & 1;
    const int nxt = cur ^ 1;
    if (kt < 15) {
      // ---- stage tile kt+1 into buf nxt (B first: oldest VMEM ops) ----
#pragma unroll
      for (int s = 0; s < 4; ++s)
        async16(projT + bsrc0 + s * (8 * D_IN) + (kt + 1) * BK,
                lds_B + nxt * BSZ + bdst0 + (s << 3) * BK);
      // X prefetch: chunk c issued at kt = 4c-2 (AFTER B -> newest 4 VMEM ops)
      if ((kt & 3) == 2 && kt < 12) {
        const int c = (kt + 2) >> 2;
#pragma unroll
        for (int i = 0; i < 4; ++i)
          xf[i] = *(const float4*)(xbase + ((c << 2) + i) * BK);
      }
      // convert chunk c = (kt+1)/4 just-in-time for its first A ds_write
      if ((kt & 3) == 3) {
        const int c = (kt + 1) >> 2;
#pragma unroll
        for (int i = 0; i < 4; ++i) {
          const float4 v = xf[i];
          ushort4 o = { f2bf(v.x), f2bf(v.y), f2bf(v.z), f2bf(v.w) };
          abf[(c << 2) + i] = o;
        }
      }
      *(ushort4*)(lds_A + nxt * ASZ + ar * A_STRIDE + (aj << 2)) = abf[kt + 1];
    }
    // ---- compute tile kt from buf cur ----
    {
      const unsigned short* Ab = lds_A + cur * ASZ;
      const unsigned short* Bb = lds_B + cur * BSZ;
#pragma unroll
      for (int kk = 0; kk < 2; ++kk) {
        v8s a, bf[4];
        a = *(const v8s*)(Ab + ((rg << 4) + lc) * A_STRIDE + (kk << 5) + (q << 3));
#pragma unroll
        for (int j = 0; j < 4; ++j) {
          const int nb = (cg << 6) + (j << 4) + lc;
          const int p  = ((kk << 2) + q) ^ (lc & 7);
          bf[j] = *(const v8s*)(Bb + nb * BK + (p << 3));
        }
#pragma unroll
        for (int j = 0; j < 4; ++j)
          acc1[j] = __builtin_amdgcn_mfma_f32_16x16x32_bf16(a, bf[j], acc1[j], 0, 0, 0);
      }
    }
    // ---- one barrier per tile; keep X prefetch (4 newest) in flight ----
    if (kt < 15) {
      if (kt == 2 || kt == 6 || kt == 10) { KBAR(4); } else { KBAR(0); }
    }
  }

  // ---- Zc = Zraw - mu_p -> LDS bf16 (buf0 region; its last readers were
  //      compute(14), synced at kt=14's barrier) + fp32 row norms ----
  unsigned short* lds_Z = lds_B;
  float mu[4];
#pragma unroll
  for (int j = 0; j < 4; ++j) mu[j] = mu_p[(cg << 6) + (j << 4) + lc];
#pragma unroll
  for (int r = 0; r < 4; ++r) {
    float s2 = 0.0f;
    const int row = (rg << 4) + (q << 2) + r;
#pragma unroll
    for (int j = 0; j < 4; ++j) {
      const float v = acc1[j][r] - mu[j];
      s2 += v * v;
      lds_Z[row * Z_STRIDE + (cg << 6) + (j << 4) + lc] = f2bf(v);
    }
    s2 += __shfl_xor(s2, 1);
    s2 += __shfl_xor(s2, 2);
    s2 += __shfl_xor(s2, 4);
    s2 += __shfl_xor(s2, 8);
    if (lc == 0) lds_part[cg][row] = s2;
  }
  __syncthreads();
  if (t < BM) {
    const float n2  = lds_part[0][t] + lds_part[1][t] + lds_part[2][t] + lds_part[3][t];
    const float nrm = sqrtf(n2);
    const float inv = 1.0f / fmaxf(nrm, 1e-12f);   // torch/jax normalize eps
    lds_inv[t] = inv;
    lds_z2[t]  = n2 * inv * inv;                   // == 1 unless degenerate
  }
  __syncthreads();

  // ---- GEMM2: dot(Zc, proto_c); wave (rg, pg=cg): 16 rows x 16 protos ----
  // protos read direct from global (32 KB, L1/L2-hot; plain logical layout)
  v8s pb[8];
  {
    const unsigned short* prow = protoB + ((cg << 4) + lc) * D_PROJ + (q << 3);
#pragma unroll
    for (int kk = 0; kk < 8; ++kk)
      pb[kk] = *(const v8s*)(prow + (kk << 5));
  }
  v4f acc2 = (v4f)(0.0f);
#pragma unroll
  for (int kk = 0; kk < 8; ++kk) {
    v8s za = *(const v8s*)(lds_Z + ((rg << 4) + lc) * Z_STRIDE + (kk << 5) + (q << 3));
    acc2 = __builtin_amdgcn_mfma_f32_16x16x32_bf16(za, pb[kk], acc2, 0, 0, 0);
  }

  // ---- epilogue: d^2 = ||Z||^2 + ||p||^2 - 2*dot*inv ; score = -sqrt(d^2) ----
  const int c  = (cg << 4) + lc;
  const float pn = pnorm2[c];
#pragma unroll
  for (int r = 0; r < 4; ++r) {
    const int row = (rg << 4) + (q << 2) + r;
    const float inv = lds_inv[row];
    const float d2  = lds_z2[row] + pn - 2.0f * acc2[r] * inv;
    out[(row0 + row) * N_C + c] = -sqrtf(fmaxf(d2, 0.0f));
  }
}

extern "C" void kernel_launch(void* const* d_in, const int* in_sizes, int n_in,
                              void* d_out, int out_size, void* d_ws, size_t ws_size,
                              hipStream_t stream) {
  const float* X      = (const float*)d_in[0];
  const float* protos = (const float*)d_in[1];
  const float* mean   = (const float*)d_in[2];
  const float* proj   = (const float*)d_in[3];
  float* out = (float*)d_out;

  unsigned short* projT  = (unsigned short*)d_ws;          // 256*1024 bf16 = 512 KB
  unsigned short* protoB = projT + D_PROJ * D_IN;          // 64*256  bf16 = 32 KB
  float*          pn2    = (float*)(protoB + N_C * D_PROJ);// 64 fp32
  float*          mup    = pn2 + N_C;                      // 256 fp32

  prep_kernel<<<96, 256, 0, stream>>>(proj, protos, mean, projT, protoB, pn2, mup);
  protonet_main<<<N_ROWS / BM, 512, 0, stream>>>(X, projT, protoB, pn2, mup, out);
}